// Round 2
// baseline (941.966 us; speedup 1.0000x reference)
//
#include <hip/hip_runtime.h>
#include <hip/hip_bf16.h>

typedef __attribute__((ext_vector_type(4))) float f32x4;
typedef __attribute__((ext_vector_type(8))) short bf16x8;
typedef __attribute__((ext_vector_type(8))) unsigned short u16x8;
typedef unsigned short u16;

#define B_ROWS 4096
#define DEPTH  1024
#define N_MEM  16384
#define QB     16
#define NB     256   // n-tile per iteration (8 waves x 32 cols)

// workspace layout (bytes)
#define XPERM_OFF   0ull            // 4096*1024*2      = 8,388,608
#define WPERM_OFF   8388608ull      // 16384*1024*2     = 33,554,432
#define WTPERM_OFF  41943040ull     // 1024*16384*2     = 33,554,432
#define OPART_OFF   75497472ull     // 2*4096*1024*4    = 33,554,432
#define ML_OFF      109051904ull    // 2*4096*2*4       = 65,536
#define WS_NEED_SPLIT   109117440ull
#define WS_NEED_NOSPLIT 75497472ull

// round-to-nearest-even fp32 -> bf16 (inputs are finite; no NaN path needed)
__device__ __forceinline__ u16 f2bf(float f) {
    union { float f; unsigned int u; } x; x.f = f;
    unsigned int u = x.u;
    unsigned int r = (u + 0x7fffu + ((u >> 16) & 1u)) >> 16;
    return (u16)r;
}

// Build MFMA-fragment-permuted bf16 copy of a row-major [ngroups*16][1024] fp32 matrix.
// Granule g = (ng*32 + kk)*64 + lane ; lane holds M[ng*16 + (lane&15)][kk*32 + (lane>>4)*8 + j]
__global__ __launch_bounds__(256) void perm_rows_kernel(const float* __restrict__ src,
                                                        u16* __restrict__ dst) {
    int g  = blockIdx.x * 256 + threadIdx.x;
    int l  = g & 63;
    int kk = (g >> 6) & 31;
    int ng = g >> 11;
    int lr = l & 15, lg = l >> 4;
    const float* p = src + (size_t)(ng * 16 + lr) * DEPTH + kk * 32 + lg * 8;
    f32x4 a = *(const f32x4*)p;
    f32x4 b = *(const f32x4*)(p + 4);
    u16x8 v;
    v[0] = f2bf(a[0]); v[1] = f2bf(a[1]); v[2] = f2bf(a[2]); v[3] = f2bf(a[3]);
    v[4] = f2bf(b[0]); v[5] = f2bf(b[1]); v[6] = f2bf(b[2]); v[7] = f2bf(b[3]);
    *(u16x8*)(dst + (size_t)g * 8) = v;
}

// Build MFMA-fragment-permuted bf16 of W-transpose.
// Granule g = (dg*512 + kkn)*64 + lane ; lane holds W[kkn*32 + (lane>>4)*8 + j][dg*16 + (lane&15)]
__global__ __launch_bounds__(256) void perm_wt_kernel(const float* __restrict__ src,
                                                      u16* __restrict__ dst) {
    int g   = blockIdx.x * 256 + threadIdx.x;
    int l   = g & 63;
    int kkn = (g >> 6) & 511;
    int dg  = g >> 15;
    int lr = l & 15, lg = l >> 4;
    int d  = dg * 16 + lr;
    int n0 = kkn * 32 + lg * 8;
    u16x8 v;
#pragma unroll
    for (int j = 0; j < 8; ++j)
        v[j] = f2bf(src[(size_t)(n0 + j) * DEPTH + d]);
    *(u16x8*)(dst + (size_t)g * 8) = v;
}

// Fused flash-style Hopfield retrieval.
// Grid: (B_ROWS/QB)*NSPLIT blocks of 512 threads (8 waves).
// Waves own n-slices (32 cols) for QK^T, d-slices (128 cols) for PV.
template <int NSPLIT>
__global__ __launch_bounds__(512, 4) void hop_main(const u16* __restrict__ xperm,
                                                   const u16* __restrict__ wperm,
                                                   const u16* __restrict__ wtperm,
                                                   float* __restrict__ opart,
                                                   float* __restrict__ mlbuf,
                                                   float* __restrict__ outd) {
    constexpr int NCHUNK = N_MEM / NSPLIT;
    constexpr int NTILES = NCHUNK / NB;

    __shared__ u16  xls[32 * 64 * 8];       // frag-permuted x block, 32 KB
    __shared__ u16  Pl[16][NB + 8];         // P (bf16), padded row stride = 528 B
    __shared__ float maxbuf[16][8];
    __shared__ float sumbuf[16][8];

    const int tid = threadIdx.x;
    const int w = tid >> 6, l = tid & 63;
    const int lr = l & 15, lg = l >> 4;
    const int bid = blockIdx.x;
    const int c  = (NSPLIT == 1) ? 0 : (bid & (NSPLIT - 1));
    const int rb = (NSPLIT == 1) ? bid : (bid >> 1);

    // stage frag-permuted x block (32 KB linear copy)
    {
        const u16x8* sp = ((const u16x8*)xperm) + (size_t)rb * 2048;
        u16x8* dp = (u16x8*)xls;
#pragma unroll
        for (int i = 0; i < 4; ++i) dp[tid + i * 512] = sp[tid + i * 512];
    }

    float mreg[4], lreg[4];
#pragma unroll
    for (int r = 0; r < 4; ++r) { mreg[r] = -1e30f; lreg[r] = 0.0f; }
    f32x4 oacc[8];
#pragma unroll
    for (int d8 = 0; d8 < 8; ++d8) oacc[d8] = (f32x4){0.f, 0.f, 0.f, 0.f};

    __syncthreads();

    const bf16x8* xv = (const bf16x8*)xls;

    for (int t = 0; t < NTILES; ++t) {
        // ---------------- scores: S[16][32w..32w+32) over K=1024 ----------------
        f32x4 s0 = {0.f, 0.f, 0.f, 0.f}, s1 = {0.f, 0.f, 0.f, 0.f};
        const int ngb = c * (NCHUNK / 16) + t * (NB / 16) + 2 * w;
        const bf16x8* w0 = ((const bf16x8*)wperm) + ((size_t)ngb * 32) * 64 + l;
        const bf16x8* w1 = w0 + 32 * 64;
#pragma unroll
        for (int kk = 0; kk < 32; ++kk) {
            bf16x8 a  = xv[kk * 64 + l];
            bf16x8 b0 = w0[kk * 64];
            bf16x8 b1 = w1[kk * 64];
            s0 = __builtin_amdgcn_mfma_f32_16x16x32_bf16(a, b0, s0, 0, 0, 0);
            s1 = __builtin_amdgcn_mfma_f32_16x16x32_bf16(a, b1, s1, 0, 0, 0);
        }

        // ---------------- online softmax ----------------
        float tmax[4];
#pragma unroll
        for (int r = 0; r < 4; ++r) tmax[r] = fmaxf(s0[r], s1[r]);
#pragma unroll
        for (int off = 1; off < 16; off <<= 1) {
#pragma unroll
            for (int r = 0; r < 4; ++r)
                tmax[r] = fmaxf(tmax[r], __shfl_xor(tmax[r], off));
        }
        if (lr == 0) {
#pragma unroll
            for (int r = 0; r < 4; ++r) maxbuf[lg * 4 + r][w] = tmax[r];
        }
        __syncthreads();   // barrier 1

        float alpha[4], p0v[4], p1v[4], tsum[4];
#pragma unroll
        for (int r = 0; r < 4; ++r) {
            const f32x4* mb = (const f32x4*)(&maxbuf[lg * 4 + r][0]);
            f32x4 a4 = mb[0], b4 = mb[1];
            float tm = fmaxf(fmaxf(fmaxf(a4[0], a4[1]), fmaxf(a4[2], a4[3])),
                             fmaxf(fmaxf(b4[0], b4[1]), fmaxf(b4[2], b4[3])));
            float mn = fmaxf(mreg[r], tm);
            alpha[r] = __expf(mreg[r] - mn);
            mreg[r]  = mn;
            p0v[r] = __expf(s0[r] - mn);
            p1v[r] = __expf(s1[r] - mn);
            tsum[r] = p0v[r] + p1v[r];
            lreg[r] *= alpha[r];
        }
#pragma unroll
        for (int off = 1; off < 16; off <<= 1) {
#pragma unroll
            for (int r = 0; r < 4; ++r)
                tsum[r] += __shfl_xor(tsum[r], off);
        }
        if (lr == 0) {
#pragma unroll
            for (int r = 0; r < 4; ++r) sumbuf[lg * 4 + r][w] = tsum[r];
        }
        // rescale O accumulator
#pragma unroll
        for (int d8 = 0; d8 < 8; ++d8) {
#pragma unroll
            for (int r = 0; r < 4; ++r) oacc[d8][r] *= alpha[r];
        }
        // write P tile (bf16)
#pragma unroll
        for (int r = 0; r < 4; ++r) {
            int R = lg * 4 + r;
            Pl[R][32 * w + lr]      = f2bf(p0v[r]);
            Pl[R][32 * w + 16 + lr] = f2bf(p1v[r]);
        }
        __syncthreads();   // barrier 2

#pragma unroll
        for (int r = 0; r < 4; ++r) {
            const f32x4* sb = (const f32x4*)(&sumbuf[lg * 4 + r][0]);
            f32x4 a4 = sb[0], b4 = sb[1];
            lreg[r] += (a4[0] + a4[1] + a4[2] + a4[3]) + (b4[0] + b4[1] + b4[2] + b4[3]);
        }

        // ---------------- PV: O[16][w*128..+128) += P @ W_tile ----------------
        const int kkb = c * (NCHUNK / 32) + t * (NB / 32);
        const bf16x8* wt0 = ((const bf16x8*)wtperm) + ((size_t)(w * 8) * 512 + kkb) * 64 + l;
#pragma unroll
        for (int kk = 0; kk < 8; ++kk) {
            bf16x8 pa = *(const bf16x8*)(&Pl[lr][kk * 32 + lg * 8]);
#pragma unroll
            for (int d8 = 0; d8 < 8; ++d8) {
                bf16x8 wb = wt0[((size_t)d8 * 512 + kk) * 64];
                oacc[d8] = __builtin_amdgcn_mfma_f32_16x16x32_bf16(pa, wb, oacc[d8], 0, 0, 0);
            }
        }
    }

    // ---------------- epilogue ----------------
    if (NSPLIT == 1) {
        float inv[4];
#pragma unroll
        for (int r = 0; r < 4; ++r) inv[r] = 1.0f / lreg[r];
        float* op = outd + (size_t)rb * QB * DEPTH;
#pragma unroll
        for (int d8 = 0; d8 < 8; ++d8) {
            int d = w * 128 + d8 * 16 + lr;
#pragma unroll
            for (int r = 0; r < 4; ++r)
                op[(size_t)(lg * 4 + r) * DEPTH + d] = oacc[d8][r] * inv[r];
        }
    } else {
        float* op = opart + ((size_t)c * B_ROWS + rb * QB) * DEPTH;
#pragma unroll
        for (int d8 = 0; d8 < 8; ++d8) {
            int d = w * 128 + d8 * 16 + lr;
#pragma unroll
            for (int r = 0; r < 4; ++r)
                op[(size_t)(lg * 4 + r) * DEPTH + d] = oacc[d8][r];
        }
        if (w == 0 && lr == 0) {
#pragma unroll
            for (int r = 0; r < 4; ++r) {
                int R = lg * 4 + r;
                size_t base = ((size_t)c * B_ROWS + rb * QB + R) * 2;
                mlbuf[base]     = mreg[r];
                mlbuf[base + 1] = lreg[r];
            }
        }
    }
}

// combine the NSPLIT=2 partials: out = (e0*O0 + e1*O1) / (e0*l0 + e1*l1)
__global__ __launch_bounds__(256) void combine_kernel(const float* __restrict__ opart,
                                                      const float* __restrict__ mlbuf,
                                                      float* __restrict__ outd) {
    int idx = blockIdx.x * 256 + threadIdx.x;    // over B*D/4 float4s
    int b = idx >> 8;                            // 256 float4 per row
    f32x4 o0 = ((const f32x4*)opart)[idx];
    f32x4 o1 = ((const f32x4*)opart)[idx + (B_ROWS * DEPTH / 4)];
    float m0 = mlbuf[(size_t)b * 2],            l0 = mlbuf[(size_t)b * 2 + 1];
    float m1 = mlbuf[((size_t)B_ROWS + b) * 2], l1 = mlbuf[((size_t)B_ROWS + b) * 2 + 1];
    float M = fmaxf(m0, m1);
    float e0 = __expf(m0 - M), e1 = __expf(m1 - M);
    float inv = 1.0f / (e0 * l0 + e1 * l1);
    ((f32x4*)outd)[idx] = (o0 * e0 + o1 * e1) * inv;
}

extern "C" void kernel_launch(void* const* d_in, const int* in_sizes, int n_in,
                              void* d_out, int out_size, void* d_ws, size_t ws_size,
                              hipStream_t stream) {
    (void)in_sizes; (void)n_in; (void)out_size;
    const float* x = (const float*)d_in[0];
    const float* W = (const float*)d_in[1];
    float* out = (float*)d_out;
    char* ws = (char*)d_ws;

    u16* xperm  = (u16*)(ws + XPERM_OFF);
    u16* wperm  = (u16*)(ws + WPERM_OFF);
    u16* wtperm = (u16*)(ws + WTPERM_OFF);

    // prep: frag-permuted bf16 copies of x, W, W^T
    perm_rows_kernel<<<2048, 256, 0, stream>>>(x, xperm);   // 256 row-groups * 32 kk * 64 lanes
    perm_rows_kernel<<<8192, 256, 0, stream>>>(W, wperm);   // 1024 row-groups
    perm_wt_kernel<<<8192, 256, 0, stream>>>(W, wtperm);    // 64 d-groups * 512 kkn

    if (ws_size >= WS_NEED_SPLIT) {
        float* opart = (float*)(ws + OPART_OFF);
        float* mlb   = (float*)(ws + ML_OFF);
        hop_main<2><<<512, 512, 0, stream>>>(xperm, wperm, wtperm, opart, mlb, out);
        // B*D/4 float4 elements -> 1,048,576 threads = 4096 blocks of 256
        combine_kernel<<<4096, 256, 0, stream>>>(opart, mlb, out);
    } else {
        hop_main<1><<<256, 512, 0, stream>>>(xperm, wperm, wtperm, nullptr, nullptr, out);
    }
}

// Round 4
// 677.858 us; speedup vs baseline: 1.3896x; 1.3896x over previous
//
#include <hip/hip_runtime.h>
#include <hip/hip_bf16.h>

typedef __attribute__((ext_vector_type(4))) float f32x4;
typedef __attribute__((ext_vector_type(8))) short bf16x8;
typedef __attribute__((ext_vector_type(8))) unsigned short u16x8;
typedef unsigned short u16;

#define B_ROWS 4096
#define DEPTH  1024
#define N_MEM  16384
#define QB     32    // x rows per block
#define NB     256   // n-tile per iteration (8 waves x 32 cols)

// workspace layout (bytes) — unchanged from R2
#define XPERM_OFF   0ull            // 4096*1024*2      = 8,388,608
#define WPERM_OFF   8388608ull      // 16384*1024*2     = 33,554,432
#define WTPERM_OFF  41943040ull     // 1024*16384*2     = 33,554,432
#define OPART_OFF   75497472ull     // 2*4096*1024*4    = 33,554,432
#define ML_OFF      109051904ull    // 2*4096*2*4       = 65,536
#define WS_NEED_SPLIT   109117440ull

// round-to-nearest-even fp32 -> bf16
__device__ __forceinline__ u16 f2bf(float f) {
    union { float f; unsigned int u; } x; x.f = f;
    unsigned int u = x.u;
    unsigned int r = (u + 0x7fffu + ((u >> 16) & 1u)) >> 16;
    return (u16)r;
}

// Build MFMA-fragment-permuted bf16 copy of a row-major [ngroups*16][1024] fp32 matrix.
// Granule g = (ng*32 + kk)*64 + lane ; lane holds M[ng*16 + (lane&15)][kk*32 + (lane>>4)*8 + j]
__global__ __launch_bounds__(256) void perm_rows_kernel(const float* __restrict__ src,
                                                        u16* __restrict__ dst) {
    int g  = blockIdx.x * 256 + threadIdx.x;
    int l  = g & 63;
    int kk = (g >> 6) & 31;
    int ng = g >> 11;
    int lr = l & 15, lg = l >> 4;
    const float* p = src + (size_t)(ng * 16 + lr) * DEPTH + kk * 32 + lg * 8;
    f32x4 a = *(const f32x4*)p;
    f32x4 b = *(const f32x4*)(p + 4);
    u16x8 v;
    v[0] = f2bf(a[0]); v[1] = f2bf(a[1]); v[2] = f2bf(a[2]); v[3] = f2bf(a[3]);
    v[4] = f2bf(b[0]); v[5] = f2bf(b[1]); v[6] = f2bf(b[2]); v[7] = f2bf(b[3]);
    *(u16x8*)(dst + (size_t)g * 8) = v;
}

// Build MFMA-fragment-permuted bf16 of W-transpose.
// Granule g = (dg*512 + kkn)*64 + lane ; lane holds W[kkn*32 + (lane>>4)*8 + j][dg*16 + (lane&15)]
__global__ __launch_bounds__(256) void perm_wt_kernel(const float* __restrict__ src,
                                                      u16* __restrict__ dst) {
    int g   = blockIdx.x * 256 + threadIdx.x;
    int l   = g & 63;
    int kkn = (g >> 6) & 511;
    int dg  = g >> 15;
    int lr = l & 15, lg = l >> 4;
    int d  = dg * 16 + lr;
    int n0 = kkn * 32 + lg * 8;
    u16x8 v;
#pragma unroll
    for (int j = 0; j < 8; ++j)
        v[j] = f2bf(src[(size_t)(n0 + j) * DEPTH + d]);
    *(u16x8*)(dst + (size_t)g * 8) = v;
}

// Fused flash-style Hopfield retrieval, QB=32 rows per block.
// Grid: (B_ROWS/QB)*NSPLIT blocks of 512 threads (8 waves).
// Waves own n-slices (32 cols) for QK^T, d-slices (128 cols) for PV.
template <int NSPLIT>
__global__ __launch_bounds__(512, 2) void hop_main(const u16* __restrict__ xperm,
                                                   const u16* __restrict__ wperm,
                                                   const u16* __restrict__ wtperm,
                                                   float* __restrict__ opart,
                                                   float* __restrict__ mlbuf,
                                                   float* __restrict__ outd) {
    constexpr int NCHUNK = N_MEM / NSPLIT;
    constexpr int NTILES = NCHUNK / NB;

    __shared__ u16  xls[2 * 32 * 64 * 8];   // frag-permuted x block (2 row-groups), 64 KB
    __shared__ u16  Pl[QB][NB + 8];         // P (bf16), row stride 528 B (132 words -> 2-way max)
    __shared__ float maxbuf[QB][8];
    __shared__ float sumbuf[QB][8];

    const int tid = threadIdx.x;
    const int w = tid >> 6, l = tid & 63;
    const int lr = l & 15, lg = l >> 4;
    const int bid = blockIdx.x;
    const int c  = (NSPLIT == 1) ? 0 : (bid & (NSPLIT - 1));
    const int rb = (NSPLIT == 1) ? bid : (bid >> 1);

    // stage frag-permuted x block (64 KB linear copy: 4096 granules of 16 B)
    {
        const u16x8* sp = ((const u16x8*)xperm) + (size_t)rb * 4096;
        u16x8* dp = (u16x8*)xls;
#pragma unroll
        for (int i = 0; i < 8; ++i) dp[tid + i * 512] = sp[tid + i * 512];
    }

    float mreg[2][4], lreg[2][4];
#pragma unroll
    for (int rg = 0; rg < 2; ++rg)
#pragma unroll
        for (int r = 0; r < 4; ++r) { mreg[rg][r] = -1e30f; lreg[rg][r] = 0.0f; }
    f32x4 oacc[2][8];
#pragma unroll
    for (int rg = 0; rg < 2; ++rg)
#pragma unroll
        for (int d8 = 0; d8 < 8; ++d8) oacc[rg][d8] = (f32x4){0.f, 0.f, 0.f, 0.f};

    __syncthreads();

    const bf16x8* xv = (const bf16x8*)xls;

    for (int t = 0; t < NTILES; ++t) {
        // ---------------- scores: S[32][32w..32w+32) over K=1024 ----------------
        f32x4 s[2][2];
#pragma unroll
        for (int rg = 0; rg < 2; ++rg)
#pragma unroll
            for (int j = 0; j < 2; ++j) s[rg][j] = (f32x4){0.f, 0.f, 0.f, 0.f};
        const int ngb = c * (NCHUNK / 16) + t * (NB / 16) + 2 * w;
        const bf16x8* w0 = ((const bf16x8*)wperm) + ((size_t)ngb * 32) * 64 + l;
        const bf16x8* w1 = w0 + 32 * 64;
#pragma unroll
        for (int kk = 0; kk < 32; ++kk) {
            bf16x8 a0 = xv[kk * 64 + l];
            bf16x8 a1 = xv[(32 + kk) * 64 + l];
            bf16x8 b0 = w0[kk * 64];
            bf16x8 b1 = w1[kk * 64];
            s[0][0] = __builtin_amdgcn_mfma_f32_16x16x32_bf16(a0, b0, s[0][0], 0, 0, 0);
            s[0][1] = __builtin_amdgcn_mfma_f32_16x16x32_bf16(a0, b1, s[0][1], 0, 0, 0);
            s[1][0] = __builtin_amdgcn_mfma_f32_16x16x32_bf16(a1, b0, s[1][0], 0, 0, 0);
            s[1][1] = __builtin_amdgcn_mfma_f32_16x16x32_bf16(a1, b1, s[1][1], 0, 0, 0);
        }

        // ---------------- online softmax ----------------
        float tmax[2][4];
#pragma unroll
        for (int rg = 0; rg < 2; ++rg)
#pragma unroll
            for (int r = 0; r < 4; ++r) tmax[rg][r] = fmaxf(s[rg][0][r], s[rg][1][r]);
#pragma unroll
        for (int off = 1; off < 16; off <<= 1) {
#pragma unroll
            for (int rg = 0; rg < 2; ++rg)
#pragma unroll
                for (int r = 0; r < 4; ++r)
                    tmax[rg][r] = fmaxf(tmax[rg][r], __shfl_xor(tmax[rg][r], off));
        }
        if (lr == 0) {
#pragma unroll
            for (int rg = 0; rg < 2; ++rg)
#pragma unroll
                for (int r = 0; r < 4; ++r) maxbuf[rg * 16 + lg * 4 + r][w] = tmax[rg][r];
        }
        __syncthreads();   // barrier 1

        float alpha[2][4], pv[2][2][4], tsum[2][4];
#pragma unroll
        for (int rg = 0; rg < 2; ++rg)
#pragma unroll
            for (int r = 0; r < 4; ++r) {
                const f32x4* mb = (const f32x4*)(&maxbuf[rg * 16 + lg * 4 + r][0]);
                f32x4 a4 = mb[0], b4 = mb[1];
                float tm = fmaxf(fmaxf(fmaxf(a4[0], a4[1]), fmaxf(a4[2], a4[3])),
                                 fmaxf(fmaxf(b4[0], b4[1]), fmaxf(b4[2], b4[3])));
                float mn = fmaxf(mreg[rg][r], tm);
                alpha[rg][r] = __expf(mreg[rg][r] - mn);
                mreg[rg][r]  = mn;
                pv[rg][0][r] = __expf(s[rg][0][r] - mn);
                pv[rg][1][r] = __expf(s[rg][1][r] - mn);
                tsum[rg][r] = pv[rg][0][r] + pv[rg][1][r];
                lreg[rg][r] *= alpha[rg][r];
            }
#pragma unroll
        for (int off = 1; off < 16; off <<= 1) {
#pragma unroll
            for (int rg = 0; rg < 2; ++rg)
#pragma unroll
                for (int r = 0; r < 4; ++r)
                    tsum[rg][r] += __shfl_xor(tsum[rg][r], off);
        }
        if (lr == 0) {
#pragma unroll
            for (int rg = 0; rg < 2; ++rg)
#pragma unroll
                for (int r = 0; r < 4; ++r) sumbuf[rg * 16 + lg * 4 + r][w] = tsum[rg][r];
        }
        // rescale O accumulator
#pragma unroll
        for (int rg = 0; rg < 2; ++rg)
#pragma unroll
            for (int d8 = 0; d8 < 8; ++d8)
#pragma unroll
                for (int r = 0; r < 4; ++r) oacc[rg][d8][r] *= alpha[rg][r];
        // write P tile (bf16)
#pragma unroll
        for (int rg = 0; rg < 2; ++rg)
#pragma unroll
            for (int r = 0; r < 4; ++r) {
                int R = rg * 16 + lg * 4 + r;
                Pl[R][32 * w + lr]      = f2bf(pv[rg][0][r]);
                Pl[R][32 * w + 16 + lr] = f2bf(pv[rg][1][r]);
            }
        __syncthreads();   // barrier 2

#pragma unroll
        for (int rg = 0; rg < 2; ++rg)
#pragma unroll
            for (int r = 0; r < 4; ++r) {
                const f32x4* sb = (const f32x4*)(&sumbuf[rg * 16 + lg * 4 + r][0]);
                f32x4 a4 = sb[0], b4 = sb[1];
                lreg[rg][r] += (a4[0] + a4[1] + a4[2] + a4[3]) + (b4[0] + b4[1] + b4[2] + b4[3]);
            }

        // ---------------- PV: O[32][w*128..+128) += P @ W_tile ----------------
        const int kkb = c * (NCHUNK / 32) + t * (NB / 32);
        const bf16x8* wt0 = ((const bf16x8*)wtperm) + ((size_t)(w * 8) * 512 + kkb) * 64 + l;
#pragma unroll
        for (int kk = 0; kk < 8; ++kk) {
            bf16x8 pa0 = *(const bf16x8*)(&Pl[lr][kk * 32 + lg * 8]);
            bf16x8 pa1 = *(const bf16x8*)(&Pl[16 + lr][kk * 32 + lg * 8]);
#pragma unroll
            for (int d8 = 0; d8 < 8; ++d8) {
                bf16x8 wb = wt0[((size_t)d8 * 512 + kk) * 64];
                oacc[0][d8] = __builtin_amdgcn_mfma_f32_16x16x32_bf16(pa0, wb, oacc[0][d8], 0, 0, 0);
                oacc[1][d8] = __builtin_amdgcn_mfma_f32_16x16x32_bf16(pa1, wb, oacc[1][d8], 0, 0, 0);
            }
        }
    }

    // ---------------- epilogue ----------------
    if (NSPLIT == 1) {
        float inv[2][4];
#pragma unroll
        for (int rg = 0; rg < 2; ++rg)
#pragma unroll
            for (int r = 0; r < 4; ++r) inv[rg][r] = 1.0f / lreg[rg][r];
        float* op = outd + (size_t)rb * QB * DEPTH;
#pragma unroll
        for (int rg = 0; rg < 2; ++rg)
#pragma unroll
            for (int d8 = 0; d8 < 8; ++d8) {
                int d = w * 128 + d8 * 16 + lr;
#pragma unroll
                for (int r = 0; r < 4; ++r)
                    op[(size_t)(rg * 16 + lg * 4 + r) * DEPTH + d] = oacc[rg][d8][r] * inv[rg][r];
            }
    } else {
        float* op = opart + ((size_t)c * B_ROWS + rb * QB) * DEPTH;
#pragma unroll
        for (int rg = 0; rg < 2; ++rg)
#pragma unroll
            for (int d8 = 0; d8 < 8; ++d8) {
                int d = w * 128 + d8 * 16 + lr;
#pragma unroll
                for (int r = 0; r < 4; ++r)
                    op[(size_t)(rg * 16 + lg * 4 + r) * DEPTH + d] = oacc[rg][d8][r];
            }
        if (w == 0 && lr == 0) {
#pragma unroll
            for (int rg = 0; rg < 2; ++rg)
#pragma unroll
                for (int r = 0; r < 4; ++r) {
                    int R = rg * 16 + lg * 4 + r;
                    size_t base = ((size_t)c * B_ROWS + rb * QB + R) * 2;
                    mlbuf[base]     = mreg[rg][r];
                    mlbuf[base + 1] = lreg[rg][r];
                }
        }
    }
}

// combine the NSPLIT=2 partials: out = (e0*O0 + e1*O1) / (e0*l0 + e1*l1)
__global__ __launch_bounds__(256) void combine_kernel(const float* __restrict__ opart,
                                                      const float* __restrict__ mlbuf,
                                                      float* __restrict__ outd) {
    int idx = blockIdx.x * 256 + threadIdx.x;    // over B*D/4 float4s
    int b = idx >> 8;                            // 256 float4 per row
    f32x4 o0 = ((const f32x4*)opart)[idx];
    f32x4 o1 = ((const f32x4*)opart)[idx + (B_ROWS * DEPTH / 4)];
    float m0 = mlbuf[(size_t)b * 2],            l0 = mlbuf[(size_t)b * 2 + 1];
    float m1 = mlbuf[((size_t)B_ROWS + b) * 2], l1 = mlbuf[((size_t)B_ROWS + b) * 2 + 1];
    float M = fmaxf(m0, m1);
    float e0 = __expf(m0 - M), e1 = __expf(m1 - M);
    float inv = 1.0f / (e0 * l0 + e1 * l1);
    ((f32x4*)outd)[idx] = (o0 * e0 + o1 * e1) * inv;
}

extern "C" void kernel_launch(void* const* d_in, const int* in_sizes, int n_in,
                              void* d_out, int out_size, void* d_ws, size_t ws_size,
                              hipStream_t stream) {
    (void)in_sizes; (void)n_in; (void)out_size;
    const float* x = (const float*)d_in[0];
    const float* W = (const float*)d_in[1];
    float* out = (float*)d_out;
    char* ws = (char*)d_ws;

    u16* xperm  = (u16*)(ws + XPERM_OFF);
    u16* wperm  = (u16*)(ws + WPERM_OFF);
    u16* wtperm = (u16*)(ws + WTPERM_OFF);

    // prep: frag-permuted bf16 copies of x, W, W^T
    perm_rows_kernel<<<2048, 256, 0, stream>>>(x, xperm);   // 256 row-groups * 32 kk * 64 lanes
    perm_rows_kernel<<<8192, 256, 0, stream>>>(W, wperm);   // 1024 row-groups
    perm_wt_kernel<<<8192, 256, 0, stream>>>(W, wtperm);    // 64 d-groups * 512 kkn

    if (ws_size >= WS_NEED_SPLIT) {
        float* opart = (float*)(ws + OPART_OFF);
        float* mlb   = (float*)(ws + ML_OFF);
        hop_main<2><<<(B_ROWS / QB) * 2, 512, 0, stream>>>(xperm, wperm, wtperm, opart, mlb, out);
        combine_kernel<<<4096, 256, 0, stream>>>(opart, mlb, out);
    } else {
        hop_main<1><<<B_ROWS / QB, 512, 0, stream>>>(xperm, wperm, wtperm, nullptr, nullptr, out);
    }
}